// Round 1
// 271.423 us; speedup vs baseline: 1.0031x; 1.0031x over previous
//
#include <hip/hip_runtime.h>
#include <hip/hip_fp16.h>

// ---------------------------------------------------------------------------
// GCN forward: h1 = relu(GCNConv(x, W1, b1)); h2 = relu(GCNConv(h1, W2, b2));
// out = h2 @ W_lin + b_lin
// N=100000, E=3200000, F_in=128, H=16, F_out=128.
// edge_index arrives as int32 [2*E]: row 0 = src, row 1 = dst.
//
// R9 pipeline (memset + 7 kernels, NO CSR):
//   memset(bucket_cnt) -> bucket_cnt -> scan -> partition (packed pairs,
//   bucket-contiguous) -> deg (per-bucket hist -> dinv) -> xform1
//   -> aggr1e: block per bucket, edge-parallel, FIXED-POINT int LDS
//      accumulators (native ds_add, no CAS loop -- R5 lesson), epilogue
//      fuses relu+W2 at BUCKET granularity (R7 lesson) -> g2 fp16
//   -> aggr2e: same gather, epilogue fuses relu+W_lin+b_lin -> out.
// R9 change (latency theory): edge loop was 8 thr/edge x 4B gathers, 64
// dependent iters/thread, VALUBusy 26% => latency-bound. Now 2 thr/edge x
// 16B dwordx4 gathers, no LDS stage / no per-tile syncthreads (waves
// free-run), manual 4x unroll with loads hoisted ahead of atomics.
// Fixed-point scale 2^18: quantization 3.8e-6/edge << fp16 4.9e-4; int sums
// are exact & order-independent (deterministic). Overflow margin ~19x.
// ---------------------------------------------------------------------------

typedef int   v4i __attribute__((ext_vector_type(4)));
typedef float v4f __attribute__((ext_vector_type(4)));
typedef float v2f __attribute__((ext_vector_type(2)));

#define NPB        256    // nodes per bucket
#define NPB_SHIFT  8
#define NB_MAX     512    // max buckets
#define PART_TILE  8192   // edges per partition block
#define PART_THR   1024
#define PT_ITERS   (PART_TILE / 4 / PART_THR)   // = 2 quads/thread
#define FXSCALE    262144.0f          // 2^18
#define FXINV      (1.0f / 262144.0f)

// Per-block LDS histogram of dst>>8, int4 loads, flushed once per block.
__global__ __launch_bounds__(256) void k_bucket_cnt(const int* __restrict__ ei,
                                                    int* __restrict__ bucket_cnt, int E) {
    __shared__ int h[NB_MAX];
    int t = threadIdx.x;
    for (int j = t; j < NB_MAX; j += 256) h[j] = 0;
    __syncthreads();
    const v4i* d4 = (const v4i*)(ei + E);
    int EQ = E >> 2;
    for (int q = blockIdx.x * 256 + t; q < EQ; q += gridDim.x * 256) {
        v4i dd = __builtin_nontemporal_load(d4 + q);
        atomicAdd(&h[dd.x >> NPB_SHIFT], 1);
        atomicAdd(&h[dd.y >> NPB_SHIFT], 1);
        atomicAdd(&h[dd.z >> NPB_SHIFT], 1);
        atomicAdd(&h[dd.w >> NPB_SHIFT], 1);
    }
    if (blockIdx.x == 0) {
        for (int e = (EQ << 2) + t; e < E; e += 256)
            atomicAdd(&h[ei[E + e] >> NPB_SHIFT], 1);
    }
    __syncthreads();
    for (int j = t; j < NB_MAX; j += 256)
        if (h[j]) atomicAdd(&bucket_cnt[j], h[j]);
}

// Exclusive scan of padded counts (pad to 16 pairs: 64B-aligned regions).
__global__ __launch_bounds__(NB_MAX) void k_bucket_scan(const int* __restrict__ bucket_cnt,
                                                        int* __restrict__ bucket_base,
                                                        int* __restrict__ bucket_cur) {
    __shared__ int s[NB_MAX];
    int t = threadIdx.x;
    int padded = (bucket_cnt[t] + 15) & ~15;
    s[t] = padded;
    __syncthreads();
    for (int off = 1; off < NB_MAX; off <<= 1) {
        int v = (t >= off) ? s[t - off] : 0;
        __syncthreads();
        s[t] += v;
        __syncthreads();
    }
    int excl = s[t] - padded;
    bucket_base[t] = excl;
    bucket_cur[t]  = excl;
}

// Partition edges into bucket-contiguous packed (src<<8 | dstlocal) runs.
__global__ __launch_bounds__(PART_THR) void k_partition(const int* __restrict__ ei,
                                                        int* __restrict__ bucket_cur,
                                                        int* __restrict__ pairs, int E) {
    __shared__ int h[NB_MAX];    // pass1: local hist; pass2: local cursor
    __shared__ int rb[NB_MAX];   // run base (absolute) per bucket
    int t = threadIdx.x;
    const v4i* s4 = (const v4i*)ei;
    const v4i* d4 = (const v4i*)(ei + E);
    int EQ = E >> 2;
    int q0 = blockIdx.x * (PART_TILE / 4);
    bool last = (blockIdx.x == gridDim.x - 1);
    v4i dsave[PT_ITERS];

    for (int j = t; j < NB_MAX; j += PART_THR) h[j] = 0;
    __syncthreads();
#pragma unroll
    for (int it = 0; it < PT_ITERS; ++it) {
        int q = q0 + it * PART_THR + t;
        v4i dd;
        if (q < EQ) {
            dd = __builtin_nontemporal_load(d4 + q);
            atomicAdd(&h[dd.x >> NPB_SHIFT], 1);
            atomicAdd(&h[dd.y >> NPB_SHIFT], 1);
            atomicAdd(&h[dd.z >> NPB_SHIFT], 1);
            atomicAdd(&h[dd.w >> NPB_SHIFT], 1);
        }
        dsave[it] = dd;
    }
    if (last) {
        for (int e = (EQ << 2) + t; e < E; e += PART_THR)
            atomicAdd(&h[ei[E + e] >> NPB_SHIFT], 1);
    }
    __syncthreads();
    for (int j = t; j < NB_MAX; j += PART_THR) {
        int c = h[j];
        rb[j] = c ? atomicAdd(&bucket_cur[j], c) : 0;
        h[j] = 0;
    }
    __syncthreads();
#pragma unroll
    for (int it = 0; it < PT_ITERS; ++it) {
        int q = q0 + it * PART_THR + t;
        if (q < EQ) {
            v4i ss = __builtin_nontemporal_load(s4 + q);
            v4i dd = dsave[it];
#pragma unroll
            for (int k = 0; k < 4; ++k) {
                int s = ss[k], d = dd[k];
                int b = d >> NPB_SHIFT;
                int pos = rb[b] + atomicAdd(&h[b], 1);
                pairs[pos] = (s << NPB_SHIFT) | (d & (NPB - 1));
            }
        }
    }
    if (last) {
        for (int e = (EQ << 2) + t; e < E; e += PART_THR) {
            int s = ei[e], d = ei[E + e];
            int b = d >> NPB_SHIFT;
            int pos = rb[b] + atomicAdd(&h[b], 1);
            pairs[pos] = (s << NPB_SHIFT) | (d & (NPB - 1));
        }
    }
}

// One block per bucket: int LDS deg hist -> dinv (deg+1 self-loop).
__global__ __launch_bounds__(256) void k_deg(const int* __restrict__ pairs,
                                             const int* __restrict__ bucket_cnt,
                                             const int* __restrict__ bucket_base,
                                             float* __restrict__ dinv, int N) {
    __shared__ int deg[NPB];
    int b = blockIdx.x, t = threadIdx.x;
    int cnt  = bucket_cnt[b];
    int base = bucket_base[b];   // 16-aligned
    deg[t] = 0;
    __syncthreads();
    const v4i* p4 = (const v4i*)(pairs + base);
    int cq = cnt >> 2;
    for (int q = t; q < cq; q += 256) {
        v4i pp = __builtin_nontemporal_load(p4 + q);
        atomicAdd(&deg[pp.x & (NPB - 1)], 1);
        atomicAdd(&deg[pp.y & (NPB - 1)], 1);
        atomicAdd(&deg[pp.z & (NPB - 1)], 1);
        atomicAdd(&deg[pp.w & (NPB - 1)], 1);
    }
    for (int i = (cq << 2) + t; i < cnt; i += 256)
        atomicAdd(&deg[pairs[base + i] & (NPB - 1)], 1);
    __syncthreads();
    int n = (b << NPB_SHIFT) + t;
    if (n < N) dinv[n] = rsqrtf((float)(deg[t] + 1));
}

// g1[n,:] = fp16( (x[n,:] @ W1) * dinv[n] )   (128 -> 16), 16 nodes per block
__global__ __launch_bounds__(256) void k_xform1(const float* __restrict__ x,
                                                const float* __restrict__ W1,
                                                const float* __restrict__ dinv,
                                                __half* __restrict__ g, int N) {
    __shared__ float xs[16][132];
    __shared__ float ws[128 * 16];
    int t = threadIdx.x;
    int n0 = blockIdx.x * 16;
    const v4f* w4 = (const v4f*)W1;
    const v4f* x4 = (const v4f*)x;
    for (int idx = t; idx < 512; idx += 256) ((v4f*)ws)[idx] = w4[idx];
    for (int idx = t; idx < 512; idx += 256) {
        int r = idx >> 5, c4 = idx & 31;
        int n = n0 + r;
        v4f v = (n < N) ? x4[(size_t)n * 32 + c4] : (v4f)(0.f);
        *(v4f*)&xs[r][c4 * 4] = v;
    }
    __syncthreads();
    int node = t >> 4, f = t & 15;
    int n = n0 + node;
    if (n < N) {
        float sum = 0.f;
#pragma unroll
        for (int k = 0; k < 128; ++k) sum += xs[node][k] * ws[k * 16 + f];
        g[(size_t)n * 16 + f] = __float2half_rn(sum * dinv[n]);
    }
}

// --- R9 edge-gather helpers: 2 lanes/edge, 16B dwordx4 gather each --------
__device__ __forceinline__ v4i gather16(const __half* __restrict__ g, int p, int fo) {
    return *(const v4i*)(g + (size_t)(p >> NPB_SHIFT) * 16 + fo);
}
__device__ __forceinline__ void commit8(int* __restrict__ acc, int p, int fo, v4i r) {
    int* a = &acc[(p & (NPB - 1)) * 17 + fo];
#pragma unroll
    for (int j = 0; j < 4; ++j) {
        float2 f = __half22float2(((const __half2*)&r)[j]);
        atomicAdd(a + 2 * j,     __float2int_rn(f.x * FXSCALE));
        atomicAdd(a + 2 * j + 1, __float2int_rn(f.y * FXSCALE));
    }
}

// Layer-1: edge-parallel fixed-point aggregation + bucket-level W2 epilogue.
// g2[d,:] = fp16( relu(dinv*(sum+self)+b1) @ W2 * dinv )
__global__ __launch_bounds__(1024) void k_aggr1e(const __half* __restrict__ g1,
                                                 const int* __restrict__ pairs,
                                                 const int* __restrict__ bucket_cnt,
                                                 const int* __restrict__ bucket_base,
                                                 const float* __restrict__ dinv,
                                                 const float* __restrict__ b1,
                                                 const float* __restrict__ W2,
                                                 __half* __restrict__ g2, int N) {
    __shared__ int   acc[NPB * 17];     // stride 17: spread banks; also h1 (float) later
    __shared__ float w2s[256];
    __shared__ float b1s[16];
    int t = threadIdx.x, b = blockIdx.x;
    int n0 = b << NPB_SHIFT;
    int cnt  = bucket_cnt[b];
    const int* pb = pairs + bucket_base[b];
    if (t < 256) w2s[t] = W2[t];
    if (t < 16)  b1s[t] = b1[t];
    for (int i = t; i < NPB * 17; i += 1024) acc[i] = 0;
    __syncthreads();
    // 512 edge slots x 2 feature-halves; waves free-run (no stage, no sync)
    int es = t >> 1, fo = (t & 1) << 3;
    int e = es;
    for (; e + 1536 < cnt; e += 2048) {
        int p0 = __builtin_nontemporal_load(pb + e);
        int p1 = __builtin_nontemporal_load(pb + e + 512);
        int p2 = __builtin_nontemporal_load(pb + e + 1024);
        int p3 = __builtin_nontemporal_load(pb + e + 1536);
        v4i r0 = gather16(g1, p0, fo);
        v4i r1 = gather16(g1, p1, fo);
        v4i r2 = gather16(g1, p2, fo);
        v4i r3 = gather16(g1, p3, fo);
        commit8(acc, p0, fo, r0);
        commit8(acc, p1, fo, r1);
        commit8(acc, p2, fo, r2);
        commit8(acc, p3, fo, r3);
    }
    for (; e < cnt; e += 512) {
        int p0 = pb[e];
        commit8(acc, p0, fo, gather16(g1, p0, fo));
    }
    __syncthreads();
    // phase A: acc -> h1 in place (each slot touched by exactly one thread)
#pragma unroll
    for (int r = 0; r < 4; ++r) {
        int idx = r * 1024 + t;          // 4096 = 256*16
        int d = idx >> 4, f = idx & 15;
        int n = n0 + d;
        float hv = 0.f;
        if (n < N) {
            float sum  = (float)acc[d * 17 + f] * FXINV;
            float self = __half2float(g1[(size_t)n * 16 + f]);
            hv = fmaxf(dinv[n] * (sum + self) + b1s[f], 0.f);
        }
        acc[d * 17 + f] = __float_as_int(hv);
    }
    __syncthreads();
    // phase B: g2 = fp16((h1 @ W2) * dinv), 2048 half2 outputs
#pragma unroll
    for (int r = 0; r < 2; ++r) {
        int idx2 = r * 1024 + t;         // 2048 = 256*8
        int d = idx2 >> 3, ff = idx2 & 7;
        int n = n0 + d;
        if (n < N) {
            float sx = 0.f, sy = 0.f;
#pragma unroll
            for (int k = 0; k < 16; ++k) {
                float hv = __int_as_float(acc[d * 17 + k]);
                sx += hv * w2s[k * 16 + 2 * ff];
                sy += hv * w2s[k * 16 + 2 * ff + 1];
            }
            float di = dinv[n];
            *(__half2*)(g2 + (size_t)n * 16 + 2 * ff) = __floats2half2_rn(sx * di, sy * di);
        }
    }
}

// Layer-2: edge-parallel fixed-point aggregation + bucket-level final GEMM.
// out[d,:] = relu(dinv*(sum+self)+b2) @ W_lin + b_lin
__global__ __launch_bounds__(1024) void k_aggr2e(const __half* __restrict__ g2,
                                                 const int* __restrict__ pairs,
                                                 const int* __restrict__ bucket_cnt,
                                                 const int* __restrict__ bucket_base,
                                                 const float* __restrict__ dinv,
                                                 const float* __restrict__ b2,
                                                 const float* __restrict__ Wl,
                                                 const float* __restrict__ bl,
                                                 float* __restrict__ out, int N) {
    __shared__ int   acc[NPB * 17];
    __shared__ float wls[16 * 128];
    __shared__ float bls[128];
    __shared__ float b2s[16];
    int t = threadIdx.x, b = blockIdx.x;
    int n0 = b << NPB_SHIFT;
    int cnt  = bucket_cnt[b];
    const int* pb = pairs + bucket_base[b];
    if (t < 512) ((v4f*)wls)[t] = ((const v4f*)Wl)[t];
    if (t < 128) bls[t] = bl[t];
    if (t < 16)  b2s[t] = b2[t];
    for (int i = t; i < NPB * 17; i += 1024) acc[i] = 0;
    __syncthreads();
    int es = t >> 1, fo = (t & 1) << 3;
    int e = es;
    for (; e + 1536 < cnt; e += 2048) {
        int p0 = __builtin_nontemporal_load(pb + e);
        int p1 = __builtin_nontemporal_load(pb + e + 512);
        int p2 = __builtin_nontemporal_load(pb + e + 1024);
        int p3 = __builtin_nontemporal_load(pb + e + 1536);
        v4i r0 = gather16(g2, p0, fo);
        v4i r1 = gather16(g2, p1, fo);
        v4i r2 = gather16(g2, p2, fo);
        v4i r3 = gather16(g2, p3, fo);
        commit8(acc, p0, fo, r0);
        commit8(acc, p1, fo, r1);
        commit8(acc, p2, fo, r2);
        commit8(acc, p3, fo, r3);
    }
    for (; e < cnt; e += 512) {
        int p0 = pb[e];
        commit8(acc, p0, fo, gather16(g2, p0, fo));
    }
    __syncthreads();
    // phase A: acc -> h2 in place
#pragma unroll
    for (int r = 0; r < 4; ++r) {
        int idx = r * 1024 + t;
        int d = idx >> 4, f = idx & 15;
        int n = n0 + d;
        float hv = 0.f;
        if (n < N) {
            float sum  = (float)acc[d * 17 + f] * FXINV;
            float self = __half2float(g2[(size_t)n * 16 + f]);
            hv = fmaxf(dinv[n] * (sum + self) + b2s[f], 0.f);
        }
        acc[d * 17 + f] = __float_as_int(hv);
    }
    __syncthreads();
    // phase B: out = h2 @ W_lin + b_lin; 16384 float2 outputs, coalesced
    const v2f* wl2 = (const v2f*)wls;
#pragma unroll
    for (int r = 0; r < 16; ++r) {
        int idx2 = r * 1024 + t;         // 16384 = 256*64
        int d = idx2 >> 6, fc = idx2 & 63;
        int n = n0 + d;
        if (n < N) {
            float ox = bls[2 * fc], oy = bls[2 * fc + 1];
#pragma unroll
            for (int k = 0; k < 16; ++k) {
                float hv = __int_as_float(acc[d * 17 + k]);
                v2f w = wl2[k * 64 + fc];
                ox += hv * w.x;
                oy += hv * w.y;
            }
            v2f o; o.x = ox; o.y = oy;
            __builtin_nontemporal_store(o, (v2f*)(out + (size_t)n * 128 + 2 * fc));
        }
    }
}

extern "C" void kernel_launch(void* const* d_in, const int* in_sizes, int n_in,
                              void* d_out, int out_size, void* d_ws, size_t ws_size,
                              hipStream_t stream) {
    const float* x  = (const float*)d_in[0];
    const int*   ei = (const int*)d_in[1];
    const float* W1 = (const float*)d_in[2];
    const float* b1 = (const float*)d_in[3];
    const float* W2 = (const float*)d_in[4];
    const float* b2 = (const float*)d_in[5];
    const float* Wl = (const float*)d_in[6];
    const float* bl = (const float*)d_in[7];
    float*       out = (float*)d_out;

    const int N = in_sizes[0] / 128;
    const int E = in_sizes[1] / 2;
    const int NB = (N + NPB - 1) >> NPB_SHIFT;   // buckets used (<= NB_MAX)

    char* ws = (char*)d_ws;
    auto carve = [&](size_t bytes) {
        char* p = ws;
        ws += (bytes + 255) & ~(size_t)255;
        return p;
    };
    int*    bucket_cnt  = (int*)carve((size_t)NB_MAX * 4);
    int*    bucket_base = (int*)carve((size_t)NB_MAX * 4);
    int*    bucket_cur  = (int*)carve((size_t)NB_MAX * 4);
    float*  dinv        = (float*)carve((size_t)N * 4);
    int*    pairs       = (int*)carve(((size_t)E + 16 * NB_MAX) * 4);
    __half* g1          = (__half*)carve((size_t)N * 16 * 2);
    __half* g2          = (__half*)carve((size_t)N * 16 * 2);
    (void)ws_size; (void)n_in; (void)out_size;

    hipMemsetAsync(bucket_cnt, 0, (size_t)NB_MAX * 4, stream);
    k_bucket_cnt<<<512, 256, 0, stream>>>(ei, bucket_cnt, E);
    k_bucket_scan<<<1, NB_MAX, 0, stream>>>(bucket_cnt, bucket_base, bucket_cur);
    k_partition<<<(E + PART_TILE - 1) / PART_TILE, PART_THR, 0, stream>>>(ei, bucket_cur, pairs, E);
    k_deg<<<NB, 256, 0, stream>>>(pairs, bucket_cnt, bucket_base, dinv, N);
    k_xform1<<<(N + 15) / 16, 256, 0, stream>>>(x, W1, dinv, g1, N);
    k_aggr1e<<<NB, 1024, 0, stream>>>(g1, pairs, bucket_cnt, bucket_base, dinv, b1, W2, g2, N);
    k_aggr2e<<<NB, 1024, 0, stream>>>(g2, pairs, bucket_cnt, bucket_base, dinv, b2, Wl, bl, out, N);
}